// Round 21
// baseline (3380.742 us; speedup 1.0000x reference)
//
#include <hip/hip_runtime.h>

// PWC-Net cost volume, fp32. B=4, C=128, H=256, W=448, 81 shifts.
// out[b, di*9+dj, h, w] = (1/128) * sum_c feat1[b,c,h,w] * feat2[b,c,h+di-4,w+dj-4]
//
// WAVE-PRIVATE LDS, ZERO BARRIERS, 4 waves/block (fixes R19's workgroup-slot
// occupancy cap: 64-thr blocks -> 10.6 waves/CU; 256-thr blocks -> up to 24).
// Wave owns (b,h,di): item = swz*4 + wid, 9216 wave-items. Lane owns 8 px
// (m = lane, 56 active). Per channel the wave stages ONLY its own feat2 row
// h+di-4 into its PRIVATE ring-3 LDS slice (wid*3*BUFB) via global_load_lds;
// sync = the wave's own counted vmcnt. No s_barrier (slices disjoint).
// f1 (cols 8m..8m+7) rides in registers, ping-pong, distance-1.
//
// LDS buffer/channel = 114 slots x 16B, interleaved permutation tau(2x)=x,
// tau(2x+1)=57+x (atom a = cols 4a-4..4a-1). Slots 0/113 = zero halo
// (written once) -> edges free. Window atoms 2m..2m+3 -> slots m, 57+m,
// m+1, 58+m: lane-stride-16B ds_read_b128 = free 2-way. Stage = 2 issues:
//   A: lanes 1..56, slot l <- src col 8l-4 ; B: lanes 0..55, slot 57+l <- 8l
// (linear LDS dest; tau pre-applied on global source). OOB rows -> zws.
//
// Body t: wait vmcnt(2) [drains f1(t), issued t-1, + stage(t), issued t-2;
// leaves stage(t+1)]; issue f1(t+1), stage(t+2); 4 ds_read + 72 FMA.
// acc[9][8]=72; demand ~80 (R19 measured); launch_bounds(256,5) cap 102.

typedef __attribute__((ext_vector_type(4))) float f32x4;

#define GLAS(p) ((const __attribute__((address_space(1))) unsigned int*)(p))
#define LDAS(p) ((__attribute__((address_space(3))) unsigned int*)(p))

__global__ __launch_bounds__(256, 5) void cv_kernel(
    const float* __restrict__ feat1,
    const float* __restrict__ feat2,
    const float* __restrict__ zws,
    float* __restrict__ out)
{
    constexpr int C = 128, H = 256, W = 448;
    constexpr size_t HW = (size_t)H * W;
    constexpr int BUFB = 114 * 16;                   // 1824 B per channel buffer
    constexpr int SLCB = 3 * BUFB;                   // 5472 B per wave slice
    __shared__ __align__(16) char lds_all[4 * SLCB]; // 21888 B per block

    const int tid  = threadIdx.x;
    const int wid  = tid >> 6;
    const int lane = tid & 63;
    const int m    = (lane < 56) ? lane : 55;
    char* lds = lds_all + wid * SLCB;                // private slice

    // XCD-contiguous mapping (2304 = 8*288, bijective); 9 di-waves of one
    // (b,h) stay adjacent -> same XCD -> rows L2-shared.
    const int swz  = (blockIdx.x & 7) * 288 + (blockIdx.x >> 3);
    const int item = swz * 4 + wid;                  // 0..9215
    const int di = item % 9;
    const int bh = item / 9;
    const int h  = bh & 255, b = bh >> 8;
    const int hr = h + di - 4;
    const bool rowok = (hr >= 0) && (hr < H);

    // Zero this slice's halo slots (0 and 113 of each ring buffer) once.
    if (lane < 3) {
        *(f32x4*)(lds + lane * BUFB)            = (f32x4){0.f, 0.f, 0.f, 0.f};
        *(f32x4*)(lds + lane * BUFB + 113 * 16) = (f32x4){0.f, 0.f, 0.f, 0.f};
    }
    asm volatile("s_waitcnt lgkmcnt(0)" ::: "memory");

    // Staging sources (tau pre-applied). OOB row -> zws (zeros), step 0.
    const float* f2base = feat2 + ((size_t)b * C * H + (size_t)(rowok ? hr : 0)) * W;
    const float* spA; const float* spB; unsigned sstep;
    if (rowok) {
        spA = f2base + (8 * lane - 4);   // lanes 1..56
        spB = f2base + (8 * lane);       // lanes 0..55
        sstep = (unsigned)HW;
    } else {
        spA = zws + lane * 4;
        spB = zws + lane * 4;
        sstep = 0u;
    }
    const bool mA = (lane >= 1) && (lane <= 56);
    const bool mB = (lane <= 55);

    // f1: own 8 cols, register ping-pong.
    unsigned f1o = (unsigned)(((b * C * H) + h) * W + 8 * m);

    // Window read offsets within a buffer (bytes).
    const int oL  = m * 16;
    const int oC1 = (57 + m) * 16;
    const int oC2 = (m + 1) * 16;
    const int oR  = (58 + m) * 16;

    float acc[9][8];
#pragma unroll
    for (int j = 0; j < 9; ++j)
#pragma unroll
        for (int p = 0; p < 8; ++p) acc[j][p] = 0.0f;

#define STAGE(NS) do { \
    if (mA) __builtin_amdgcn_global_load_lds(GLAS(spA), LDAS(lds + (NS) * BUFB), 16, 0, 0); \
    if (mB) __builtin_amdgcn_global_load_lds(GLAS(spB), LDAS(lds + (NS) * BUFB + 912), 16, 0, 0); \
    spA += sstep; spB += sstep; } while (0)

#define COMP(BUF) do { \
    const char* lb = lds + (BUF) * BUFB; \
    const f32x4 L  = *(const f32x4*)(lb + oL); \
    const f32x4 C1 = *(const f32x4*)(lb + oC1); \
    const f32x4 C2 = *(const f32x4*)(lb + oC2); \
    const f32x4 R  = *(const f32x4*)(lb + oR); \
    const float w[16] = {L.x, L.y, L.z, L.w, C1.x, C1.y, C1.z, C1.w, \
                         C2.x, C2.y, C2.z, C2.w, R.x, R.y, R.z, R.w}; \
    const float a[8]  = {f1c0.x, f1c0.y, f1c0.z, f1c0.w, \
                         f1c1.x, f1c1.y, f1c1.z, f1c1.w}; \
    _Pragma("unroll") \
    for (int dj = 0; dj < 9; ++dj) { \
        _Pragma("unroll") \
        for (int p = 0; p < 8; ++p) \
            acc[dj][p] = fmaf(a[p], w[dj + p], acc[dj][p]); \
    } } while (0)

// MODE 0: steady | 1: no stage (t=126) | 2: tail (t=127)
#define BODY(BUF, NS, MODE) do { \
    if ((MODE) <= 1) asm volatile("s_waitcnt vmcnt(2)" ::: "memory"); \
    else             asm volatile("s_waitcnt vmcnt(0)" ::: "memory"); \
    __builtin_amdgcn_sched_barrier(0); \
    f32x4 f1n0, f1n1; \
    if ((MODE) <= 1) { \
        f1n0 = *(const f32x4*)(feat1 + f1o); \
        f1n1 = *(const f32x4*)(feat1 + f1o + 4); \
        f1o += (unsigned)HW; \
    } \
    if ((MODE) == 0) STAGE(NS); \
    __builtin_amdgcn_sched_barrier(0); \
    COMP(BUF); \
    if ((MODE) <= 1) { f1c0 = f1n0; f1c1 = f1n1; } \
  } while (0)

    // Prologue: stage ch0 -> buf0; f1(0); stage ch1 -> buf1.
    STAGE(0);
    f32x4 f1c0 = *(const f32x4*)(feat1 + f1o);
    f32x4 f1c1 = *(const f32x4*)(feat1 + f1o + 4);
    f1o += (unsigned)HW;
    STAGE(1);

    // Bodies 0..125 (42 x 3), tail 126 (no stage), 127 (drain).
#pragma unroll 1
    for (int g = 0; g < 42; ++g) {
        BODY(0, 2, 0);
        BODY(1, 0, 0);
        BODY(2, 1, 0);
    }
    BODY(0, 2, 1);   // t = 126: f1(127) only
    BODY(1, 0, 2);   // t = 127

#undef STAGE
#undef COMP
#undef BODY

    if (lane < 56) {
        const float s = 1.0f / 128.0f;
        float* ob = out + (((size_t)(b * 81 + di * 9)) * H + h) * W + 8 * m;
#pragma unroll
        for (int dj = 0; dj < 9; ++dj) {
            f32x4 o0 = {acc[dj][0] * s, acc[dj][1] * s,
                        acc[dj][2] * s, acc[dj][3] * s};
            f32x4 o1 = {acc[dj][4] * s, acc[dj][5] * s,
                        acc[dj][6] * s, acc[dj][7] * s};
            float* op = ob + (size_t)dj * HW;
            *(f32x4*)(op)     = o0;
            *(f32x4*)(op + 4) = o1;
        }
    }
}

extern "C" void kernel_launch(void* const* d_in, const int* in_sizes, int n_in,
                              void* d_out, int out_size, void* d_ws, size_t ws_size,
                              hipStream_t stream) {
    const float* feat1 = (const float*)d_in[0];
    const float* feat2 = (const float*)d_in[1];
    float* out = (float*)d_out;
    // 1 KiB zeros: stage source for vertically-OOB feat2 rows (lane*4 floats).
    hipMemsetAsync(d_ws, 0, 1024, stream);
    cv_kernel<<<dim3(2304), dim3(256), 0, stream>>>(
        feat1, feat2, (const float*)d_ws, out);
}

// Round 22
// 298.781 us; speedup vs baseline: 11.3151x; 11.3151x over previous
//
#include <hip/hip_runtime.h>

// PWC-Net cost volume, fp32. B=4, C=128, H=256, W=448, 81 shifts.
// out[b, di*9+dj, h, w] = (1/128) * sum_c feat1[b,c,h,w] * feat2[b,c,h+di-4,w+dj-4]
//
// WAVE-PRIVATE LDS, ZERO BARRIERS, 4 waves/block. Wave owns (b,h,di):
// item = swz*4 + wid, 9216 wave-items. Lane owns 8 px (m = lane, 56 active).
// Per channel the wave stages ONLY its own feat2 row h+di-4 into its PRIVATE
// ring-3 LDS slice (wid*3*BUFB) via global_load_lds; sync = the wave's own
// counted vmcnt. No s_barrier (slices disjoint). f1 in registers, ping-pong.
//
// launch_bounds(256,3) -> VGPR cap 170 (R19's proven config; R20's (256,5)
// = cap 102 < demand ~126 -> acc spilled to scratch, 11x slowdown. acc72
// kernels need cap >= 170: R7/R9/R15/R18/R20 all died to cap < demand).
//
// LDS buffer/channel = 114 slots x 16B, interleaved permutation tau(2x)=x,
// tau(2x+1)=57+x (atom a = cols 4a-4..4a-1). Slots 0/113 = zero halo
// (written once) -> edges free. Window atoms 2m..2m+3 -> slots m, 57+m,
// m+1, 58+m: lane-stride-16B ds_read_b128 = free 2-way. Stage = 2 issues:
//   A: lanes 1..56, slot l <- src col 8l-4 ; B: lanes 0..55, slot 57+l <- 8l
// (linear LDS dest; tau pre-applied on global source). OOB rows -> zws.
//
// Body t: wait vmcnt(2) [drains f1(t), issued t-1, + stage(t), issued t-2;
// leaves stage(t+1)]; issue f1(t+1), stage(t+2); 4 ds_read + 72 FMA.

typedef __attribute__((ext_vector_type(4))) float f32x4;

#define GLAS(p) ((const __attribute__((address_space(1))) unsigned int*)(p))
#define LDAS(p) ((__attribute__((address_space(3))) unsigned int*)(p))

__global__ __launch_bounds__(256, 3) void cv_kernel(
    const float* __restrict__ feat1,
    const float* __restrict__ feat2,
    const float* __restrict__ zws,
    float* __restrict__ out)
{
    constexpr int C = 128, H = 256, W = 448;
    constexpr size_t HW = (size_t)H * W;
    constexpr int BUFB = 114 * 16;                   // 1824 B per channel buffer
    constexpr int SLCB = 3 * BUFB;                   // 5472 B per wave slice
    __shared__ __align__(16) char lds_all[4 * SLCB]; // 21888 B per block

    const int tid  = threadIdx.x;
    const int wid  = tid >> 6;
    const int lane = tid & 63;
    const int m    = (lane < 56) ? lane : 55;
    char* lds = lds_all + wid * SLCB;                // private slice

    // XCD-contiguous mapping (2304 = 8*288, bijective); 9 di-waves of one
    // (b,h) stay adjacent -> same XCD -> rows L2-shared.
    const int swz  = (blockIdx.x & 7) * 288 + (blockIdx.x >> 3);
    const int item = swz * 4 + wid;                  // 0..9215
    const int di = item % 9;
    const int bh = item / 9;
    const int h  = bh & 255, b = bh >> 8;
    const int hr = h + di - 4;
    const bool rowok = (hr >= 0) && (hr < H);

    // Zero this slice's halo slots (0 and 113 of each ring buffer) once.
    if (lane < 3) {
        *(f32x4*)(lds + lane * BUFB)            = (f32x4){0.f, 0.f, 0.f, 0.f};
        *(f32x4*)(lds + lane * BUFB + 113 * 16) = (f32x4){0.f, 0.f, 0.f, 0.f};
    }
    asm volatile("s_waitcnt lgkmcnt(0)" ::: "memory");

    // Staging sources (tau pre-applied). OOB row -> zws (zeros), step 0.
    const float* f2base = feat2 + ((size_t)b * C * H + (size_t)(rowok ? hr : 0)) * W;
    const float* spA; const float* spB; unsigned sstep;
    if (rowok) {
        spA = f2base + (8 * lane - 4);   // lanes 1..56
        spB = f2base + (8 * lane);       // lanes 0..55
        sstep = (unsigned)HW;
    } else {
        spA = zws + lane * 4;
        spB = zws + lane * 4;
        sstep = 0u;
    }
    const bool mA = (lane >= 1) && (lane <= 56);
    const bool mB = (lane <= 55);

    // f1: own 8 cols, register ping-pong.
    unsigned f1o = (unsigned)(((b * C * H) + h) * W + 8 * m);

    // Window read offsets within a buffer (bytes).
    const int oL  = m * 16;
    const int oC1 = (57 + m) * 16;
    const int oC2 = (m + 1) * 16;
    const int oR  = (58 + m) * 16;

    float acc[9][8];
#pragma unroll
    for (int j = 0; j < 9; ++j)
#pragma unroll
        for (int p = 0; p < 8; ++p) acc[j][p] = 0.0f;

#define STAGE(NS) do { \
    if (mA) __builtin_amdgcn_global_load_lds(GLAS(spA), LDAS(lds + (NS) * BUFB), 16, 0, 0); \
    if (mB) __builtin_amdgcn_global_load_lds(GLAS(spB), LDAS(lds + (NS) * BUFB + 912), 16, 0, 0); \
    spA += sstep; spB += sstep; } while (0)

#define COMP(BUF) do { \
    const char* lb = lds + (BUF) * BUFB; \
    const f32x4 L  = *(const f32x4*)(lb + oL); \
    const f32x4 C1 = *(const f32x4*)(lb + oC1); \
    const f32x4 C2 = *(const f32x4*)(lb + oC2); \
    const f32x4 R  = *(const f32x4*)(lb + oR); \
    const float w[16] = {L.x, L.y, L.z, L.w, C1.x, C1.y, C1.z, C1.w, \
                         C2.x, C2.y, C2.z, C2.w, R.x, R.y, R.z, R.w}; \
    const float a[8]  = {f1c0.x, f1c0.y, f1c0.z, f1c0.w, \
                         f1c1.x, f1c1.y, f1c1.z, f1c1.w}; \
    _Pragma("unroll") \
    for (int dj = 0; dj < 9; ++dj) { \
        _Pragma("unroll") \
        for (int p = 0; p < 8; ++p) \
            acc[dj][p] = fmaf(a[p], w[dj + p], acc[dj][p]); \
    } } while (0)

// MODE 0: steady | 1: no stage (t=126) | 2: tail (t=127)
#define BODY(BUF, NS, MODE) do { \
    if ((MODE) <= 1) asm volatile("s_waitcnt vmcnt(2)" ::: "memory"); \
    else             asm volatile("s_waitcnt vmcnt(0)" ::: "memory"); \
    __builtin_amdgcn_sched_barrier(0); \
    f32x4 f1n0, f1n1; \
    if ((MODE) <= 1) { \
        f1n0 = *(const f32x4*)(feat1 + f1o); \
        f1n1 = *(const f32x4*)(feat1 + f1o + 4); \
        f1o += (unsigned)HW; \
    } \
    if ((MODE) == 0) STAGE(NS); \
    __builtin_amdgcn_sched_barrier(0); \
    COMP(BUF); \
    if ((MODE) <= 1) { f1c0 = f1n0; f1c1 = f1n1; } \
  } while (0)

    // Prologue: stage ch0 -> buf0; f1(0); stage ch1 -> buf1.
    STAGE(0);
    f32x4 f1c0 = *(const f32x4*)(feat1 + f1o);
    f32x4 f1c1 = *(const f32x4*)(feat1 + f1o + 4);
    f1o += (unsigned)HW;
    STAGE(1);

    // Bodies 0..125 (42 x 3), tail 126 (no stage), 127 (drain).
#pragma unroll 1
    for (int g = 0; g < 42; ++g) {
        BODY(0, 2, 0);
        BODY(1, 0, 0);
        BODY(2, 1, 0);
    }
    BODY(0, 2, 1);   // t = 126: f1(127) only
    BODY(1, 0, 2);   // t = 127

#undef STAGE
#undef COMP
#undef BODY

    if (lane < 56) {
        const float s = 1.0f / 128.0f;
        float* ob = out + (((size_t)(b * 81 + di * 9)) * H + h) * W + 8 * m;
#pragma unroll
        for (int dj = 0; dj < 9; ++dj) {
            f32x4 o0 = {acc[dj][0] * s, acc[dj][1] * s,
                        acc[dj][2] * s, acc[dj][3] * s};
            f32x4 o1 = {acc[dj][4] * s, acc[dj][5] * s,
                        acc[dj][6] * s, acc[dj][7] * s};
            float* op = ob + (size_t)dj * HW;
            *(f32x4*)(op)     = o0;
            *(f32x4*)(op + 4) = o1;
        }
    }
}

extern "C" void kernel_launch(void* const* d_in, const int* in_sizes, int n_in,
                              void* d_out, int out_size, void* d_ws, size_t ws_size,
                              hipStream_t stream) {
    const float* feat1 = (const float*)d_in[0];
    const float* feat2 = (const float*)d_in[1];
    float* out = (float*)d_out;
    // 1 KiB zeros: stage source for vertically-OOB feat2 rows (lane*4 floats).
    hipMemsetAsync(d_ws, 0, 1024, stream);
    cv_kernel<<<dim3(2304), dim3(256), 0, stream>>>(
        feat1, feat2, (const float*)d_ws, out);
}

// Round 23
// 259.491 us; speedup vs baseline: 13.0283x; 1.1514x over previous
//
#include <hip/hip_runtime.h>

// PWC-Net cost volume, fp32. B=4, C=128, H=256, W=448, 81 shifts.
// out[b, di*9+dj, h, w] = (1/128) * sum_c feat1[b,c,h,w] * feat2[b,c,h+di-4,w+dj-4]
//
// R16 structure (best point: 277us) + deeper ring. Block = (b,h), 1024 thr /
// 16 waves. Thread owns ONE 4-px quad: it = tid -> di = it/112, G = it%112
// (1008 active). acc[9][4] = 36 AGPR-class regs; arch VGPR ~48 -> no spill
// at cap 128, ~6 waves/SIMD by regs, 1 resident 16-wave block (+partial).
//
// Per channel one LDS buffer: 10 rows x 114 atoms(16B). Rows 0..8 = feat2
// h-4..h+4 (OOB rows staged as zeros from zws), row 9 = feat1 h. Atom a
// covers cols 4a-4..4a-1; atoms 0/113 = halo, zeroed once, never staged.
// Thread reads f2 atoms G,G+1,G+2 + f1 atom G+1 (4x ds_read_b128,
// lane-stride-16B = free 2-way aliasing).
//
// RING-4, stage distance 3, drain-old counted vmcnt leaving TWO bundles in
// flight: body t waits vmcnt(2*nIss) (drains bundle t, issued 3 bodies ago
// ~1800cy cover; leaves t+1, t+2), barrier (publishes buf t; all reads of
// buf (t-1)&3 completed -> safe for stage(t+3) to overwrite it), stages
// bundle t+3, computes buf t&3. No sched_barrier between STAGE and COMP
// (different buffers; compiler may interleave). Stage = 20 issues (10 rows
// x 2 half-rows): wave wid takes j = wid (+16+wid if wid<4); nIss = wid<4
// ? 2 : 1.

typedef __attribute__((ext_vector_type(4))) float f32x4;

#define GLAS(p) ((const __attribute__((address_space(1))) unsigned int*)(p))
#define LDAS(p) ((__attribute__((address_space(3))) unsigned int*)(p))

__global__ __launch_bounds__(1024, 4) void cv_kernel(
    const float* __restrict__ feat1,
    const float* __restrict__ feat2,
    const float* __restrict__ zws,
    float* __restrict__ out)
{
    constexpr int C = 128, H = 256, W = 448;
    constexpr size_t HW = (size_t)H * W;
    constexpr int ROWB = 114 * 16;     // 1824 B
    constexpr int BUFB = 10 * ROWB;    // 18240 B
    __shared__ __align__(16) char f2s[4 * BUFB];   // 72960 B

    const int tid  = threadIdx.x;
    const int wid  = tid >> 6;
    const int lane = tid & 63;

    // XCD-contiguous (b,h) mapping (1024 = 8*128, bijective)
    const int lin = (blockIdx.x & 7) * 128 + (blockIdx.x >> 3);
    const int b = lin >> 8, h = lin & 255;

    const int it = (tid < 1008) ? tid : 1007;
    const int di = it / 112;
    const int G  = it - di * 112;      // 0..111

    // Zero LDS once (halo atoms 0/113 persist; staged atoms overwritten).
    for (int i = tid; i < (int)sizeof(f2s) / 16; i += 1024)
        *(f32x4*)(f2s + i * 16) = (f32x4){0.f, 0.f, 0.f, 0.f};

    // Staging descriptors. Issue j: row r = j>>1 (0..9), half hf = j&1.
    // Lanes 0..55: 16B from row_base + hf*224 + lane*4 floats
    //   -> dest r*ROWB + 16 + hf*896 (atoms 1..112 linear).
    // r==9 -> feat1 row h; else feat2 row h+r-4 (OOB -> zws, step 0).
    const int nIss = (wid < 4) ? 2 : 1;
    const float* sp[2]; unsigned sstep[2]; int sdst[2];
#pragma unroll
    for (int k = 0; k < 2; ++k) {
        if (k < nIss) {
            const int j  = wid + 16 * k;
            const int r  = j >> 1, hf = j & 1;
            const int colf = hf * 224 + ((lane < 56) ? lane * 4 : 220);
            if (r == 9) {
                sp[k] = feat1 + ((size_t)b * C * H + (size_t)h) * W + colf;
                sstep[k] = (unsigned)HW;
            } else {
                const int hr = h + r - 4;
                const bool ok = (hr >= 0) && (hr < H);
                sp[k] = ok ? (feat2 + ((size_t)b * C * H + (size_t)hr) * W + colf) : zws;
                sstep[k] = ok ? (unsigned)HW : 0u;
            }
            sdst[k] = r * ROWB + 16 + hf * 896;
        }
    }

    // Read offsets: f2 atoms G..G+2 of row di; f1 atom G+1 of row 9.
    const int r2o = di * ROWB + G * 16;
    const int r1o = 9 * ROWB + (G + 1) * 16;

    float acc[9][4];
#pragma unroll
    for (int j = 0; j < 9; ++j)
#pragma unroll
        for (int p = 0; p < 4; ++p) acc[j][p] = 0.0f;

    __syncthreads();   // LDS zeros visible before first stage lands

#define STAGE(BUFOFS) do { \
    _Pragma("unroll") \
    for (int k = 0; k < 2; ++k) { \
        if (k < nIss) { \
            if (lane < 56) \
                __builtin_amdgcn_global_load_lds(GLAS(sp[k]), \
                    LDAS(f2s + (BUFOFS) + sdst[k]), 16, 0, 0); \
            sp[k] += sstep[k]; \
        } \
    } } while (0)

// MODE 0: wait 2n + stage | 1: wait 2n | 2: wait n | 3: wait 0
#define BODY(BUF, NBUF, MODE) do { \
    if ((MODE) <= 1) { \
        if (wid < 4) asm volatile("s_waitcnt vmcnt(4)" ::: "memory"); \
        else         asm volatile("s_waitcnt vmcnt(2)" ::: "memory"); \
    } else if ((MODE) == 2) { \
        if (wid < 4) asm volatile("s_waitcnt vmcnt(2)" ::: "memory"); \
        else         asm volatile("s_waitcnt vmcnt(1)" ::: "memory"); \
    } else { \
        asm volatile("s_waitcnt vmcnt(0)" ::: "memory"); \
    } \
    __builtin_amdgcn_s_barrier(); \
    __builtin_amdgcn_sched_barrier(0); \
    if ((MODE) == 0) STAGE((NBUF) * BUFB); \
    { \
        const char* lb = f2s + (BUF) * BUFB; \
        const f32x4 L  = *(const f32x4*)(lb + r2o); \
        const f32x4 Cq = *(const f32x4*)(lb + r2o + 16); \
        const f32x4 R  = *(const f32x4*)(lb + r2o + 32); \
        const f32x4 A  = *(const f32x4*)(lb + r1o); \
        const float w[12] = {L.x, L.y, L.z, L.w, Cq.x, Cq.y, Cq.z, Cq.w, \
                             R.x, R.y, R.z, R.w}; \
        const float a[4] = {A.x, A.y, A.z, A.w}; \
        _Pragma("unroll") \
        for (int dj = 0; dj < 9; ++dj) { \
            _Pragma("unroll") \
            for (int p = 0; p < 4; ++p) \
                acc[dj][p] = fmaf(a[p], w[dj + p], acc[dj][p]); \
        } \
    } } while (0)

    // Prologue: bundles 0,1,2 into buffers 0,1,2 (3 bundles outstanding).
    STAGE(0 * BUFB);
    STAGE(1 * BUFB);
    STAGE(2 * BUFB);

    // Bodies 0..123 (31 x 4): body t stages bundle t+3 into buf (t+3)&3.
#pragma unroll 1
    for (int g = 0; g < 31; ++g) {
        BODY(0, 3, 0);
        BODY(1, 0, 0);
        BODY(2, 1, 0);
        BODY(3, 2, 0);
    }
    BODY(0, 3, 0);   // t=124: stages bundle 127 -> buf 3
    BODY(1, 0, 1);   // t=125: wait 2n (drains 125; leaves 126,127)
    BODY(2, 1, 2);   // t=126: wait n  (leaves 127)
    BODY(3, 2, 3);   // t=127: wait 0

#undef STAGE
#undef BODY

    if (tid < 1008) {
        const float s = 1.0f / 128.0f;
        float* ob = out + (((size_t)(b * 81 + di * 9)) * H + h) * W + G * 4;
#pragma unroll
        for (int dj = 0; dj < 9; ++dj) {
            f32x4 ov = {acc[dj][0] * s, acc[dj][1] * s,
                        acc[dj][2] * s, acc[dj][3] * s};
            *(f32x4*)(ob + (size_t)dj * HW) = ov;
        }
    }
}

extern "C" void kernel_launch(void* const* d_in, const int* in_sizes, int n_in,
                              void* d_out, int out_size, void* d_ws, size_t ws_size,
                              hipStream_t stream) {
    const float* feat1 = (const float*)d_in[0];
    const float* feat2 = (const float*)d_in[1];
    float* out = (float*)d_out;
    // 256 zeroed bytes: broadcast-source for vertically-OOB feat2 rows.
    hipMemsetAsync(d_ws, 0, 256, stream);
    cv_kernel<<<dim3(1024), dim3(1024), 0, stream>>>(
        feat1, feat2, (const float*)d_ws, out);
}